// Round 4
// baseline (3725.084 us; speedup 1.0000x reference)
//
#include <hip/hip_runtime.h>

typedef short bf16x8 __attribute__((ext_vector_type(8)));
typedef float f32x4 __attribute__((ext_vector_type(4)));

#define LOG2E 1.44269504088896340736f

__device__ __forceinline__ unsigned short f2bf(float x) {
    unsigned u = __builtin_bit_cast(unsigned, x);
    return (unsigned short)((u + 0x7fffu + ((u >> 16) & 1u)) >> 16);
}

// 512 blocks x 512 threads (2 blocks/CU). Block owns 16 batch rows; wave owns
// 16 hidden channels across all 4 gate strips. Persistent loop over 2048 steps.
// Gate pre-activations are pre-scaled by -log2e (i,f,o) / +2log2e (g) so the
// tail is exp2-based; one rcp serves sigmoid(f), sigmoid(i)*tanh(g):
//   r3 = rcp((1+yf)(1+yi)(1+yg)); sf = (1+yi)(1+yg)*r3; ig = (yg-1)(1+yf)*r3
// h ring is 16 deep so the batched output GEMM needs no extra barrier.
__global__ __launch_bounds__(512, 4)
void lstm_persist(const float* __restrict__ zP, const float* __restrict__ condP,
                  const float* __restrict__ startP, const float* __restrict__ WihP,
                  const float* __restrict__ WhhP, const float* __restrict__ bihP,
                  const float* __restrict__ bhhP, const float* __restrict__ WoutP,
                  const float* __restrict__ boutP, float* __restrict__ outP)
{
    // h history ring: 16 slots x 16 rows x 128 hidden (bf16), XOR-swizzled rows
    __shared__ unsigned short hist[16 * 16 * 128];   // 64 KiB
    char* const lds = (char*)hist;

    const int tid  = threadIdx.x;
    const int wave = tid >> 6;
    const int lane = tid & 63;
    const int lo   = lane & 15;       // col within fragment
    const int gq   = lane >> 4;       // 0..3
    const int r0   = blockIdx.x * 16; // global batch-row base
    const int hid0 = wave * 16;       // this wave's hidden slice

    const float K2 = 2.0f * LOG2E;
    const float ss[4] = { -LOG2E, -LOG2E, 2.0f * LOG2E, -LOG2E };

    // ---- B fragments of W' = ss[s]*(W_hh + Wx @ W_out)  (bf16, registers) ----
    float wxs0[4], wxs1[4], bias[4];
    bf16x8 bfrag[4][4];
    #pragma unroll
    for (int s = 0; s < 4; ++s) {
        const int col = s * 128 + hid0 + lo;
        const float wx0 = WihP[col * 39 + 0];
        const float wx1 = WihP[col * 39 + 1];
        wxs0[s] = ss[s] * wx0;
        wxs1[s] = ss[s] * wx1;
        bias[s] = bihP[col] + bhhP[col];
        #pragma unroll
        for (int kt = 0; kt < 4; ++kt) {
            bf16x8 f;
            #pragma unroll
            for (int j = 0; j < 8; ++j) {
                const int k = kt * 32 + gq * 8 + j;
                const float w = WhhP[col * 128 + k]
                              + wx0 * WoutP[k] + wx1 * WoutP[128 + k];
                f[j] = (short)f2bf(ss[s] * w);
            }
            bfrag[s][kt] = f;
        }
    }

    // ---- W_out B-fragments for the batched output GEMM ----
    bf16x8 wof[4];
    #pragma unroll
    for (int kt = 0; kt < 4; ++kt) {
        bf16x8 f;
        #pragma unroll
        for (int j = 0; j < 8; ++j) {
            const int k = kt * 32 + gq * 8 + j;
            f[j] = (lo < 2) ? (short)f2bf(WoutP[lo * 128 + k]) : (short)0;
        }
        wof[kt] = f;
    }
    const float bo = (lo < 2) ? boutP[lo] : 0.0f;

    // ---- static projection into registers (C-fragment layout, pre-scaled) ----
    f32x4 sp[4];  // [strip], components = rr (row = gq*4+rr)
    #pragma unroll
    for (int s = 0; s < 4; ++s)
        #pragma unroll
        for (int rr = 0; rr < 4; ++rr)
            sp[s][rr] = bias[s];

    for (int j = 0; j < 32; ++j) {   // z part
        float w[4];
        #pragma unroll
        for (int s = 0; s < 4; ++s) w[s] = WihP[(s * 128 + hid0 + lo) * 39 + 2 + j];
        #pragma unroll
        for (int rr = 0; rr < 4; ++rr) {
            const int row = r0 + gq * 4 + rr;
            const float si = zP[row * 32 + j];
            #pragma unroll
            for (int s = 0; s < 4; ++s) sp[s][rr] += si * w[s];
        }
    }
    for (int j = 0; j < 4; ++j) {    // condition part
        float w[4];
        #pragma unroll
        for (int s = 0; s < 4; ++s) w[s] = WihP[(s * 128 + hid0 + lo) * 39 + 34 + j];
        #pragma unroll
        for (int rr = 0; rr < 4; ++rr) {
            const int row = r0 + gq * 4 + rr;
            const float si = condP[row * 4 + j];
            #pragma unroll
            for (int s = 0; s < 4; ++s) sp[s][rr] += si * w[s];
        }
    }
    #pragma unroll
    for (int s = 0; s < 4; ++s) {    // dt term + scale
        const float w = 0.05f * WihP[(s * 128 + hid0 + lo) * 39 + 38];
        #pragma unroll
        for (int rr = 0; rr < 4; ++rr) sp[s][rr] = ss[s] * (sp[s][rr] + w);
    }

    // ---- LDS offsets (swizzle: byte ^= (row&7)<<4) ----
    int wroff[4];
    #pragma unroll
    for (int rr = 0; rr < 4; ++rr) {
        const int row = gq * 4 + rr;
        wroff[rr] = (row * 256 + (hid0 + lo) * 2) ^ ((row & 7) << 4);
    }
    int rdoff[4];
    #pragma unroll
    for (int kt = 0; kt < 4; ++kt)
        rdoff[kt] = (lo * 256 + kt * 64 + gq * 16) ^ ((lo & 7) << 4);

    // ---- LSTM cell state ----
    f32x4 cst = f32x4{0.f, 0.f, 0.f, 0.f};

    // activation tail: scaled gates -> (h bf16 -> LDS), updates c
    auto tail = [&](f32x4 (&acc)[4], const int wbase) {
        float h[4];
        #pragma unroll
        for (int rr = 0; rr < 4; ++rr) {
            const float yi = __builtin_amdgcn_exp2f(__builtin_fminf(acc[0][rr], 40.f));
            const float yf = __builtin_amdgcn_exp2f(__builtin_fminf(acc[1][rr], 40.f));
            const float yg = __builtin_amdgcn_exp2f(__builtin_fminf(acc[2][rr], 40.f));
            const float yo = __builtin_amdgcn_exp2f(__builtin_fminf(acc[3][rr], 40.f));
            const float pf  = 1.0f + yf;
            const float pig = (1.0f + yi) * (1.0f + yg);
            const float r3  = __builtin_amdgcn_rcpf(pf * pig);
            const float sf  = pig * r3;                       // sigmoid(f)
            const float ig  = (yg - 1.0f) * pf * r3;          // sigmoid(i)*tanh(g)
            const float cn  = __builtin_fmaf(sf, cst[rr], ig);
            cst[rr] = cn;
            const float yc  = __builtin_amdgcn_exp2f(__builtin_fminf(cn * K2, 40.f));
            const float roc = __builtin_amdgcn_rcpf((1.0f + yo) * (1.0f + yc));
            h[rr] = (yc - 1.0f) * roc;                        // sigmoid(o)*tanh(c)
        }
        unsigned p01, p23;
        asm("v_cvt_pk_bf16_f32 %0, %1, %2" : "=v"(p01) : "v"(h[0]), "v"(h[1]));
        asm("v_cvt_pk_bf16_f32 %0, %1, %2" : "=v"(p23) : "v"(h[2]), "v"(h[3]));
        *(unsigned short*)(lds + wbase + wroff[0]) = (unsigned short)(p01 & 0xffffu);
        *(unsigned short*)(lds + wbase + wroff[1]) = (unsigned short)(p01 >> 16);
        *(unsigned short*)(lds + wbase + wroff[2]) = (unsigned short)(p23 & 0xffffu);
        *(unsigned short*)(lds + wbase + wroff[3]) = (unsigned short)(p23 >> 16);
    };

    // ---- step 0: gates = ss*(x_start@Wx.T) + SP (pure VALU, h0 = c0 = 0) ----
    {
        f32x4 acc0[4];
        #pragma unroll
        for (int s = 0; s < 4; ++s) acc0[s] = sp[s];
        #pragma unroll
        for (int rr = 0; rr < 4; ++rr) {
            const int row = r0 + gq * 4 + rr;
            const float x0 = startP[row * 2 + 0];
            const float x1 = startP[row * 2 + 1];
            #pragma unroll
            for (int s = 0; s < 4; ++s)
                acc0[s][rr] += x0 * wxs0[s] + x1 * wxs1[s];
        }
        tail(acc0, 0);   // slot 0
    }
    // fold bx = ss*(Wx@b_out) into sp for t >= 1
    #pragma unroll
    for (int s = 0; s < 4; ++s) {
        const float bx = wxs0[s] * boutP[0] + wxs1[s] * boutP[1];
        #pragma unroll
        for (int rr = 0; rr < 4; ++rr) sp[s][rr] += bx;
    }
    __syncthreads();

    // anti-convoy stagger: odd blocks sleep ~half a step so the two
    // co-resident blocks on a CU run anti-phased (sleep uses no pipe).
    if (blockIdx.x & 1) {
        asm volatile("s_sleep 7\n s_sleep 7\n s_sleep 7\n s_sleep 7\n s_sleep 7");
    }

    // ---- main recurrence ----
    #pragma unroll 1
    for (int t = 1; t < 2048; ++t) {
        const int rbase = ((t - 1) & 15) * 4096;
        const int wbase = (t & 15) * 4096;

        // every 8 steps: batched output GEMM over history slots holding
        // h_{t-8..t-1} (slot base ((t-8)&15)). Ring is 16 deep, so these
        // slots are not rewritten until steps t+8..t+15 -> no extra barrier;
        // overlaps with this step's MFMA phase.
        if ((t & 7) == 0) {
            const int sbase = (wave + ((t - 8) & 15)) * 4096;  // slot (t-8+wave)&15
            f32x4 xacc = f32x4{0.f, 0.f, 0.f, 0.f};
            #pragma unroll
            for (int kt = 0; kt < 4; ++kt) {
                const bf16x8 a = __builtin_bit_cast(bf16x8,
                    *(const f32x4*)(lds + sbase + rdoff[kt]));
                xacc = __builtin_amdgcn_mfma_f32_16x16x32_bf16(a, wof[kt], xacc, 0, 0, 0);
            }
            const int tg = t - 8 + wave;
            if (lo < 2) {
                #pragma unroll
                for (int rr = 0; rr < 4; ++rr) {
                    const int row = gq * 4 + rr;
                    outP[(size_t)(r0 + row) * 4096 + tg * 2 + lo] = xacc[rr] + bo;
                }
            }
        }

        bf16x8 af[4];
        #pragma unroll
        for (int kt = 0; kt < 4; ++kt)
            af[kt] = __builtin_bit_cast(bf16x8, *(const f32x4*)(lds + rbase + rdoff[kt]));

        f32x4 acc[4];
        #pragma unroll
        for (int s = 0; s < 4; ++s) {
            f32x4 a = sp[s];
            #pragma unroll
            for (int kt = 0; kt < 4; ++kt)
                a = __builtin_amdgcn_mfma_f32_16x16x32_bf16(af[kt], bfrag[s][kt], a, 0, 0, 0);
            acc[s] = a;
        }
        tail(acc, wbase);
        __syncthreads();
    }

    // final output batch: h_{2040..2047} live in slots 8..15
    {
        const int sbase = (wave + 8) * 4096;   // ((2048-8)&15) = 8
        f32x4 xacc = f32x4{0.f, 0.f, 0.f, 0.f};
        #pragma unroll
        for (int kt = 0; kt < 4; ++kt) {
            const bf16x8 a = __builtin_bit_cast(bf16x8,
                *(const f32x4*)(lds + sbase + rdoff[kt]));
            xacc = __builtin_amdgcn_mfma_f32_16x16x32_bf16(a, wof[kt], xacc, 0, 0, 0);
        }
        const int tg = 2040 + wave;
        if (lo < 2) {
            #pragma unroll
            for (int rr = 0; rr < 4; ++rr) {
                const int row = gq * 4 + rr;
                outP[(size_t)(r0 + row) * 4096 + tg * 2 + lo] = xacc[rr] + bo;
            }
        }
    }
}

extern "C" void kernel_launch(void* const* d_in, const int* in_sizes, int n_in,
                              void* d_out, int out_size, void* d_ws, size_t ws_size,
                              hipStream_t stream) {
    const float* z    = (const float*)d_in[0];
    const float* cond = (const float*)d_in[1];
    const float* strt = (const float*)d_in[2];
    const float* Wih  = (const float*)d_in[3];
    const float* Whh  = (const float*)d_in[4];
    const float* bih  = (const float*)d_in[5];
    const float* bhh  = (const float*)d_in[6];
    const float* Wout = (const float*)d_in[7];
    const float* bout = (const float*)d_in[8];
    float* out = (float*)d_out;

    hipLaunchKernelGGL(lstm_persist, dim3(512), dim3(512), 0, stream,
                       z, cond, strt, Wih, Whh, bih, bhh, Wout, bout, out);
}